// Round 6
// baseline (297.473 us; speedup 1.0000x reference)
//
#include <hip/hip_runtime.h>
#include <math.h>

#define Bn 16
#define Nn 1024
#define Dn 128

typedef unsigned short ushort;
typedef unsigned long long u64;
typedef short short8 __attribute__((ext_vector_type(8)));
typedef float f32x4 __attribute__((ext_vector_type(4)));
typedef ushort us8 __attribute__((ext_vector_type(8)));
typedef ushort us4 __attribute__((ext_vector_type(4)));

__device__ __forceinline__ ushort f2bf(float f) {
    unsigned u = __float_as_uint(f);
    u += 0x7fff + ((u >> 16) & 1);           // RTN-even
    return (ushort)(u >> 16);
}
__device__ __forceinline__ float bf2f(ushort s) {
    return __uint_as_float(((unsigned)s) << 16);
}

// ---- async global->LDS staging. 16B/lane, LDS dst = uniform base + lane*16.
#if defined(__has_builtin)
#if __has_builtin(__builtin_amdgcn_global_load_lds)
#define HAVE_GLL 1
#endif
#endif
#ifndef HAVE_GLL
#define HAVE_GLL 0
#endif

typedef __attribute__((address_space(1))) void as1_t;
typedef __attribute__((address_space(3))) void as3_t;

__device__ __forceinline__ void stage_group(const void* gbase, void* lbase, int lane) {
#if HAVE_GLL
    __builtin_amdgcn_global_load_lds((as1_t*)((const char*)gbase + lane * 16),
                                     (as3_t*)lbase, 16, 0, 0);
#else
    *(us8*)((char*)lbase + lane * 16) = *(const us8*)((const char*)gbase + lane * 16);
#endif
}

// manual grid barrier (all 256 blocks resident: 1 block/CU). bar[0]=cnt bar[1]=flag
__device__ __forceinline__ void gbar(int* bar, int phase, int nblk) {
    __syncthreads();
    if (threadIdx.x == 0) {
        __threadfence();
        int old = atomicAdd(&bar[0], 1);
        if (old == phase * nblk - 1)
            __hip_atomic_store(&bar[1], phase, __ATOMIC_RELAXED, __HIP_MEMORY_SCOPE_AGENT);
        while (__hip_atomic_load(&bar[1], __ATOMIC_RELAXED, __HIP_MEMORY_SCOPE_AGENT) < phase)
            __builtin_amdgcn_s_sleep(2);
        __threadfence();
    }
    __syncthreads();
}

// Fragment layouts (us8 units of 16 B), tile = 16 rows, unit u = lane = q*16 + m.
//   h16f/g16f:  group = rt_global*4 + kc          (kc 0..3),  unit q*16+m
//   Ef:         group = (b*64 + rt)*32 + kc       (kc 0..31), unit q*16+m
//   Tf:         group = (b*8  + kt)*32 + kc,                  unit q*16+m
// bm ballot layout: bm[(row_global*4 + chunk)*4 + j], j=col&3, bit=(col>>2)&63

// ================= K0: weight split + S=A+A^T split + Z init + adj ballot + bar init ==========
__global__ __launch_bounds__(256) void k_ph0(const float* __restrict__ Ww,
                                             const float* __restrict__ A,
                                             const float* __restrict__ adj,
                                             ushort* __restrict__ Whi, ushort* __restrict__ Wlo,
                                             ushort* __restrict__ Shi, ushort* __restrict__ Slo,
                                             float* __restrict__ Z, u64* __restrict__ bm,
                                             int* __restrict__ bar) {
    int L = blockIdx.x, t = threadIdx.x;
    if (L < 64) {
        int i = L * 256 + t;
        float w = Ww[i];
        ushort wh = f2bf(w);
        Whi[i] = wh;
        Wlo[i] = f2bf(w - bf2f(wh));
        int e = i >> 7, d = i & 127;
        float s = A[i] + A[d * Dn + e];      // S = A + A^T (symmetrized bilinear form)
        ushort sh = f2bf(s);
        Shi[i] = sh;
        Slo[i] = f2bf(s - bf2f(sh));
        Z[i] = (float)Nn;                    // non-edge exp(0) mass, m=0 shift
        if (i == 0) { bar[0] = 0; bar[1] = 0; }
    }
    int gwv = L * 4 + (t >> 6);
    int lane = t & 63;
    #pragma unroll 4
    for (int it = 0; it < 16; ++it) {
        int pair = gwv * 16 + it;            // (row,chunk), 65536 total
        const float* p = adj + (size_t)pair * 256 + lane * 4;
        float4 v = *(const float4*)p;
        u64 b0 = __ballot(v.x > 0.f);
        u64 b1 = __ballot(v.y > 0.f);
        u64 b2 = __ballot(v.z > 0.f);
        u64 b3 = __ballot(v.w > 0.f);
        if (lane == 0) {
            u64* d = bm + (size_t)pair * 4;
            d[0] = b0; d[1] = b1; d[2] = b2; d[3] = b3;
        }
    }
}

// ================= K1: h = xW^T+b ; g = h@S ; fragment bf16 out; x LDS-staged =================
__global__ __launch_bounds__(256) void k_h(const float* __restrict__ x,
                                           const float* __restrict__ Wb,
                                           const ushort* __restrict__ Whi,
                                           const ushort* __restrict__ Wlo,
                                           const ushort* __restrict__ Shi,
                                           const ushort* __restrict__ Slo,
                                           float* __restrict__ h,
                                           ushort* __restrict__ h16f,
                                           ushort* __restrict__ g16f) {
    int I0 = blockIdx.x * 16;
    int t = threadIdx.x, w = t >> 6, lane = t & 63;
    int m = lane & 15, q = lane >> 4;

    __shared__ float xs[16][Dn + 4];
    __shared__ float hs[16][Dn + 4];
    __shared__ float gs_[16][Dn + 4];

    {   // coalesced x stage: thread t -> row t>>4, cols (t&15)*8..+8
        int r = t >> 4, c8 = (t & 15) * 8;
        const float* src = x + (size_t)(I0 + r) * Dn + c8;
        *(float4*)&xs[r][c8]     = *(const float4*)(src);
        *(float4*)&xs[r][c8 + 4] = *(const float4*)(src + 4);
    }
    __syncthreads();

    f32x4 acc0 = {0,0,0,0}, acc1 = {0,0,0,0};
    #pragma unroll
    for (int ks = 0; ks < 4; ++ks) {
        int k0 = q * 8 + ks * 32;
        float v[8]; short8 ahi, alo;
        *(float4*)(v)     = *(const float4*)(&xs[m][k0]);
        *(float4*)(v + 4) = *(const float4*)(&xs[m][k0 + 4]);
        #pragma unroll
        for (int j = 0; j < 8; ++j) {
            ushort hi = f2bf(v[j]);
            ahi[j] = (short)hi;
            alo[j] = (short)f2bf(v[j] - bf2f(hi));
        }
        #pragma unroll
        for (int nn = 0; nn < 2; ++nn) {
            int brow = (w * 2 + nn) * 16 + m;
            short8 bhi = __builtin_bit_cast(short8, ((const us8*)(Whi + (size_t)brow * Dn))[q + ks * 4]);
            short8 blo = __builtin_bit_cast(short8, ((const us8*)(Wlo + (size_t)brow * Dn))[q + ks * 4]);
            f32x4 acc = nn ? acc1 : acc0;
            acc = __builtin_amdgcn_mfma_f32_16x16x32_bf16(ahi, bhi, acc, 0, 0, 0);
            acc = __builtin_amdgcn_mfma_f32_16x16x32_bf16(alo, bhi, acc, 0, 0, 0);
            acc = __builtin_amdgcn_mfma_f32_16x16x32_bf16(ahi, blo, acc, 0, 0, 0);
            if (nn) acc1 = acc; else acc0 = acc;
        }
    }
    #pragma unroll
    for (int nn = 0; nn < 2; ++nn) {
        int col = (w * 2 + nn) * 16 + m;
        float bias = Wb[col];
        f32x4 acc = nn ? acc1 : acc0;
        #pragma unroll
        for (int r = 0; r < 4; ++r) {
            int rl = q * 4 + r;
            float hv = acc[r] + bias;
            h[(size_t)(I0 + rl) * Dn + col] = hv;
            hs[rl][col] = hv;
        }
    }
    __syncthreads();

    f32x4 bcc0 = {0,0,0,0}, bcc1 = {0,0,0,0};
    #pragma unroll
    for (int ks = 0; ks < 4; ++ks) {
        int k0 = q * 8 + ks * 32;
        float v[8]; short8 ahi, alo;
        *(float4*)(v)     = *(const float4*)(&hs[m][k0]);
        *(float4*)(v + 4) = *(const float4*)(&hs[m][k0 + 4]);
        #pragma unroll
        for (int j = 0; j < 8; ++j) {
            ushort hi = f2bf(v[j]);
            ahi[j] = (short)hi;
            alo[j] = (short)f2bf(v[j] - bf2f(hi));
        }
        #pragma unroll
        for (int nn = 0; nn < 2; ++nn) {
            int brow = (w * 2 + nn) * 16 + m;
            short8 bhi = __builtin_bit_cast(short8, ((const us8*)(Shi + (size_t)brow * Dn))[q + ks * 4]);
            short8 blo = __builtin_bit_cast(short8, ((const us8*)(Slo + (size_t)brow * Dn))[q + ks * 4]);
            f32x4 acc = nn ? bcc1 : bcc0;
            acc = __builtin_amdgcn_mfma_f32_16x16x32_bf16(ahi, bhi, acc, 0, 0, 0);
            acc = __builtin_amdgcn_mfma_f32_16x16x32_bf16(alo, bhi, acc, 0, 0, 0);
            acc = __builtin_amdgcn_mfma_f32_16x16x32_bf16(ahi, blo, acc, 0, 0, 0);
            if (nn) bcc1 = acc; else bcc0 = acc;
        }
    }
    #pragma unroll
    for (int nn = 0; nn < 2; ++nn) {
        int col = (w * 2 + nn) * 16 + m;
        f32x4 acc = nn ? bcc1 : bcc0;
        #pragma unroll
        for (int r = 0; r < 4; ++r)
            gs_[q * 4 + r][col] = acc[r];
    }
    __syncthreads();

    {   // fragment-layout conversion (unit order q*16+m)
        int kc = t >> 6, mm = (t >> 2) & 15, qq = t & 3;
        int cb = kc * 32 + qq * 8;
        us8 oh, oa;
        #pragma unroll
        for (int e = 0; e < 8; ++e) {
            oh[e] = f2bf(hs[mm][cb + e]);
            oa[e] = f2bf(gs_[mm][cb + e]);
        }
        size_t U = (size_t)(I0 >> 4) * 256 + kc * 64 + qq * 16 + mm;
        ((us8*)h16f)[U] = oh;
        ((us8*)g16f)[U] = oa;
    }
}

// ================= K3: scores = g_I . h_J, A-frags in regs, h_J staged, linear frag reads ======
__global__ __launch_bounds__(256, 4) void k_scores(const ushort* __restrict__ g16f,
                                                   const ushort* __restrict__ h16f,
                                                   const u64* __restrict__ bm,
                                                   ushort* __restrict__ Ef,
                                                   float* __restrict__ Z) {
    int L = blockIdx.x;
    int b    = ((L & 7) << 1) | (L >> 11);        // XCD-grouped batches
    int tile = (L >> 3) & 255;
    int I0 = (tile >> 4) << 6;
    int J0 = (tile & 15) << 6;
    int t = threadIdx.x, wid = t >> 6, lane = t & 63;
    int loff = lane * 16;

    __shared__ __align__(16) char smem[18432];    // 16K h_J stage / 17K sc alias + 1K cz
    float (*sc)[68] = (float(*)[68])smem;
    float (*cz)[64] = (float(*)[64])(smem + 17408);

    {   // stage h_J: 16 x 1KB groups (rt_l = g>>2, kk = g&3)
        const char* hbp = (const char*)h16f + (size_t)b * 262144;
        for (int g = wid; g < 16; g += 4) {
            int rt_l = g >> 2, kk = g & 3;
            stage_group(hbp + ((size_t)((J0 >> 4) + rt_l) * 256 + kk * 64) * 16,
                        smem + g * 1024, lane);
        }
    }
    short8 afr[4];
    {   // g_I fragments straight to registers
        const char* gbp = (const char*)g16f + (size_t)b * 262144
                        + (size_t)((I0 >> 4) + wid) * 4096 + loff;
        #pragma unroll
        for (int ks = 0; ks < 4; ++ks)
            afr[ks] = __builtin_bit_cast(short8, *(const us8*)(gbp + ks * 1024));
    }
    __syncthreads();

    f32x4 acc[4] = {};
    #pragma unroll
    for (int ks = 0; ks < 4; ++ks) {
        #pragma unroll
        for (int nt = 0; nt < 4; ++nt) {
            short8 bb = __builtin_bit_cast(short8,
                *(const us8*)(smem + (nt * 4 + ks) * 1024 + loff));
            acc[nt] = __builtin_amdgcn_mfma_f32_16x16x32_bf16(afr[ks], bb, acc[nt], 0, 0, 0);
        }
    }
    __syncthreads();

    {
        int m = lane & 15, q = lane >> 4;
        #pragma unroll
        for (int nt = 0; nt < 4; ++nt)
            #pragma unroll
            for (int r = 0; r < 4; ++r)
                sc[wid * 16 + q * 4 + r][nt * 16 + m] = acc[nt][r];
    }
    __syncthreads();

    int row16 = t >> 4, c = t & 15;
    int bitc = ((J0 >> 2) & 63) + c;
    float colsum[4] = {0.f, 0.f, 0.f, 0.f};
    #pragma unroll
    for (int it = 0; it < 4; ++it) {
        int row = it * 16 + row16;
        const u64* wp = bm + ((size_t)(b * Nn + I0 + row) * 4 + (J0 >> 8)) * 4;
        u64 wj[4] = {wp[0], wp[1], wp[2], wp[3]};
        float s4[4];
        *(float4*)s4 = *(const float4*)(&sc[row][c * 4]);
        us4 e4;
        #pragma unroll
        for (int j = 0; j < 4; ++j) {
            float ex = __expf(s4[j]);
            bool on = (wj[j] >> bitc) & 1;
            e4[j] = f2bf(on ? ex : 0.f);
            colsum[j] += on ? (ex - 1.0f) : 0.f;
        }
        size_t base = ((((size_t)b * 64 + (I0 >> 4) + it) * 32 + (J0 >> 5) + (c >> 3)) * 512)
                    + (size_t)((c & 7) >> 1) * 128 + row16 * 8 + (c & 1) * 4;
        *(us4*)(Ef + base) = e4;
    }
    #pragma unroll
    for (int j = 0; j < 4; ++j) {
        colsum[j] += __shfl_xor(colsum[j], 16, 64);
        colsum[j] += __shfl_xor(colsum[j], 32, 64);
    }
    if (lane < 16) {
        #pragma unroll
        for (int j = 0; j < 4; ++j) cz[wid][lane * 4 + j] = colsum[j];
    }
    __syncthreads();
    if (t < 64) {
        float s = cz[0][t] + cz[1][t] + cz[2][t] + cz[3][t];
        atomicAdd(&Z[b * Nn + J0 + t], s);
    }
}

// ================= K5: fused prep + 3 hops. Independent waves (2/SIMD), global->VGPR loads, ====
// ================= grid barriers only between hops. h and 1/Z live in registers throughout. ===
__global__ __launch_bounds__(512, 1) void k_hops(const ushort* __restrict__ Ef,
                                                 const float* __restrict__ h,
                                                 const float* __restrict__ Z,
                                                 const float* __restrict__ gw,
                                                 const float* __restrict__ gb,
                                                 ushort* __restrict__ T0,
                                                 ushort* __restrict__ T1,
                                                 float* __restrict__ out,
                                                 int* __restrict__ bar) {
    int L = blockIdx.x;                           // 256 blocks = 1/CU (co-resident)
    int b   = ((L & 7) << 1) | (L >> 7);          // XCD-grouped batches
    int rtp = (L >> 3) & 15;                      // block covers rt = rtp*4 + {0..3}
    int t = threadIdx.x, w = t >> 6, lane = t & 63;
    int m = lane & 15, q = lane >> 4;
    int rr = w & 3, ch = w >> 2;                  // wave: row-tile rr, col-half ch
    int rt = rtp * 4 + rr;
    int I0 = rt << 4;
    int loff = lane * 16;

    __shared__ ushort tt[4][128][16];             // 16 KB transpose scratch
    __shared__ float gpart[4][16][2];

    const char* ebase = (const char*)Ef + (size_t)(b * 64 + rt) * 32768 + loff;

    float gb0 = gb[0];
    float gwa[4], gwz[4];
    #pragma unroll
    for (int nt2 = 0; nt2 < 4; ++nt2) {
        gwa[nt2] = gw[ch * 64 + nt2 * 16 + m];
        gwz[nt2] = gw[Dn + ch * 64 + nt2 * 16 + m];
    }

    // ---- prep: h and 1/Z into registers (reused across all hops); T0 = (h/Z)^T frags ----
    float hv[4][4], izr[4];
    size_t hbase = ((size_t)b * Nn + I0) * Dn;
    #pragma unroll
    for (int r = 0; r < 4; ++r) {
        int row = q * 4 + r;
        izr[r] = 1.0f / Z[b * Nn + I0 + row];
        #pragma unroll
        for (int nt2 = 0; nt2 < 4; ++nt2)
            hv[nt2][r] = h[hbase + (size_t)row * Dn + ch * 64 + nt2 * 16 + m];
    }
    #pragma unroll
    for (int r = 0; r < 4; ++r)
        #pragma unroll
        for (int nt2 = 0; nt2 < 4; ++nt2)
            tt[rr][ch * 64 + nt2 * 16 + m][q * 4 + r] = f2bf(hv[nt2][r] * izr[r]);
    __syncthreads();
    {   // T0 write: 512 threads x 2 us8 (fragment layout, unit q*16+m)
        int k = t >> 2, v0 = t & 3;
        #pragma unroll
        for (int u2 = 0; u2 < 2; ++u2) {
            int v = v0 * 2 + u2, jh = v >> 2, qv = v & 3;
            size_t G = (size_t)(k >> 4) * 32 + rtp * 2 + jh;
            *(us8*)(T0 + (size_t)b * 131072 + G * 512 + (size_t)(k & 15) * 8 + qv * 128) =
                *(const us8*)&tt[jh * 2 + (qv >> 1)][k][(qv & 1) * 8];
        }
    }
    gbar(bar, 1, 256);

    // ---- 3 hops ----
    #pragma unroll 1
    for (int hop = 0; hop < 3; ++hop) {
        const char* tb = (const char*)(hop == 1 ? T1 : T0)
                       + (size_t)b * 262144 + (size_t)ch * 131072 + loff;
        ushort* Tout = (hop == 0) ? T1 : T0;

        f32x4 acc[4] = {};
        #pragma unroll 2
        for (int cch = 0; cch < 8; ++cch) {       // unroll 2: next-chunk loads overlap MFMAs
            const char* eb = ebase + (size_t)cch * 4096;
            const char* tc = tb + (size_t)cch * 4096;
            short8 ea[4];
            #pragma unroll
            for (int kk = 0; kk < 4; ++kk)
                ea[kk] = __builtin_bit_cast(short8, *(const us8*)(eb + kk * 1024));
            #pragma unroll
            for (int kk = 0; kk < 4; ++kk) {
                #pragma unroll
                for (int nt2 = 0; nt2 < 4; ++nt2) {
                    short8 bf = __builtin_bit_cast(short8,
                        *(const us8*)(tc + (size_t)nt2 * 32768 + kk * 1024));
                    acc[nt2] = __builtin_amdgcn_mfma_f32_16x16x32_bf16(ea[kk], bf, acc[nt2], 0, 0, 0);
                }
            }
        }

        // gate: relu + m-lane shuffle reduce + cross col-half partial via LDS
        float gsr[4];
        #pragma unroll
        for (int r = 0; r < 4; ++r) {
            float gs = 0.f;
            #pragma unroll
            for (int nt2 = 0; nt2 < 4; ++nt2) {
                float az = fmaxf(acc[nt2][r], 0.f);
                acc[nt2][r] = az;
                gs += hv[nt2][r] * gwa[nt2] + az * gwz[nt2];
            }
            gs += __shfl_xor(gs, 1, 64);
            gs += __shfl_xor(gs, 2, 64);
            gs += __shfl_xor(gs, 4, 64);
            gs += __shfl_xor(gs, 8, 64);
            gsr[r] = gs;
        }
        if (m == 0) {
            #pragma unroll
            for (int r = 0; r < 4; ++r) gpart[rr][q * 4 + r][ch] = gsr[r];
        }
        __syncthreads();

        float coef[4];
        #pragma unroll
        for (int r = 0; r < 4; ++r) {
            float g2 = gpart[rr][q * 4 + r][0] + gpart[rr][q * 4 + r][1];
            coef[r] = 1.0f / (1.0f + __expf(-(g2 + gb0)));
        }

        if (hop == 2) {
            #pragma unroll
            for (int r = 0; r < 4; ++r) {
                int row = q * 4 + r;
                float cc = coef[r];
                #pragma unroll
                for (int nt2 = 0; nt2 < 4; ++nt2)
                    out[hbase + (size_t)row * Dn + ch * 64 + nt2 * 16 + m] =
                        cc * hv[nt2][r] + (1.f - cc) * acc[nt2][r];
            }
        } else {
            #pragma unroll
            for (int r = 0; r < 4; ++r) {
                float cc = coef[r];
                float iz = izr[r];
                #pragma unroll
                for (int nt2 = 0; nt2 < 4; ++nt2) {
                    float v = cc * hv[nt2][r] + (1.f - cc) * acc[nt2][r];
                    tt[rr][ch * 64 + nt2 * 16 + m][q * 4 + r] = f2bf(v * iz);
                }
            }
            __syncthreads();
            {   // Tout write: 512 threads x 2 us8
                int k = t >> 2, v0 = t & 3;
                #pragma unroll
                for (int u2 = 0; u2 < 2; ++u2) {
                    int v = v0 * 2 + u2, jh = v >> 2, qv = v & 3;
                    size_t G = (size_t)(k >> 4) * 32 + rtp * 2 + jh;
                    *(us8*)(Tout + (size_t)b * 131072 + G * 512 + (size_t)(k & 15) * 8 + qv * 128) =
                        *(const us8*)&tt[jh * 2 + (qv >> 1)][k][(qv & 1) * 8];
                }
            }
            gbar(bar, 2 + hop, 256);
        }
    }
}

extern "C" void kernel_launch(void* const* d_in, const int* in_sizes, int n_in,
                              void* d_out, int out_size, void* d_ws, size_t ws_size,
                              hipStream_t stream) {
    const float* x    = (const float*)d_in[0];   // [B,N,128]
    const float* adj  = (const float*)d_in[1];   // [B,N,N]
    const float* Ww   = (const float*)d_in[2];   // [128,128]
    const float* Wb   = (const float*)d_in[3];   // [128]
    const float* A    = (const float*)d_in[4];   // [128,128]
    const float* gw   = (const float*)d_in[5];   // [1,256]
    const float* gb   = (const float*)d_in[6];   // [1]
    float* out = (float*)d_out;                  // [B,N,128] f32

    char* ws = (char*)d_ws;
    float*  h    = (float*)(ws);                          // 8 MB f32
    ushort* Ta   = (ushort*)(ws + (8u << 20));            // 4 MB: h16f, then Tf buf A
    ushort* Tb   = (ushort*)(ws + (12u << 20));           // 4 MB: g16f, then Tf buf B
    ushort* E    = (ushort*)(ws + (16u << 20));           // 32 MB (fragment layout)
    float*  Z    = (float*)(ws + (48u << 20));            // 64 KB
    ushort* Whi  = (ushort*)(ws + (48u << 20) + (64u << 10));
    ushort* Wlo  = (ushort*)(ws + (48u << 20) + (96u << 10));
    ushort* Shi  = (ushort*)(ws + (48u << 20) + (128u << 10));
    ushort* Slo  = (ushort*)(ws + (48u << 20) + (160u << 10));
    u64*    bm   = (u64*)(ws + (48u << 20) + (192u << 10));  // 2 MB bitmask
    int*    bar  = (int*)(ws + (51u << 20));                 // grid-barrier cnt/flag
    // total ~51 MB

    k_ph0   <<<1024, 256, 0, stream>>>(Ww, A, adj, Whi, Wlo, Shi, Slo, Z, bm, bar);
    k_h     <<<1024, 256, 0, stream>>>(x, Wb, Whi, Wlo, Shi, Slo, h, Ta, Tb);
    k_scores<<<4096, 256, 0, stream>>>(Tb, Ta, bm, E, Z);
    k_hops  <<<256,  512, 0, stream>>>(E, h, Z, gw, gb, Ta, Tb, out, bar);
}

// Round 7
// 191.592 us; speedup vs baseline: 1.5526x; 1.5526x over previous
//
#include <hip/hip_runtime.h>
#include <math.h>

#define Bn 16
#define Nn 1024
#define Dn 128

typedef unsigned short ushort;
typedef unsigned long long u64;
typedef short short8 __attribute__((ext_vector_type(8)));
typedef float f32x4 __attribute__((ext_vector_type(4)));
typedef ushort us8 __attribute__((ext_vector_type(8)));
typedef ushort us4 __attribute__((ext_vector_type(4)));

__device__ __forceinline__ ushort f2bf(float f) {
    unsigned u = __float_as_uint(f);
    u += 0x7fff + ((u >> 16) & 1);           // RTN-even
    return (ushort)(u >> 16);
}
__device__ __forceinline__ float bf2f(ushort s) {
    return __uint_as_float(((unsigned)s) << 16);
}

// ---- async global->LDS staging. 16B/lane, LDS dst = uniform base + lane*16.
#if defined(__has_builtin)
#if __has_builtin(__builtin_amdgcn_global_load_lds)
#define HAVE_GLL 1
#endif
#endif
#ifndef HAVE_GLL
#define HAVE_GLL 0
#endif

typedef __attribute__((address_space(1))) void as1_t;
typedef __attribute__((address_space(3))) void as3_t;

__device__ __forceinline__ void stage_group(const void* gbase, void* lbase, int lane) {
#if HAVE_GLL
    __builtin_amdgcn_global_load_lds((as1_t*)((const char*)gbase + lane * 16),
                                     (as3_t*)lbase, 16, 0, 0);
#else
    *(us8*)((char*)lbase + lane * 16) = *(const us8*)((const char*)gbase + lane * 16);
#endif
}

// Fragment layouts (us8 units of 16 B), tile = 16 rows, unit u = lane = q*16 + m.
//   h16f/g16f:  group = rt_global*4 + kc          (kc 0..3),  unit q*16+m
//   Ef:         group = (b*64 + rt)*32 + kc       (kc 0..31), unit q*16+m
//   Tf:         group = (b*8  + kt)*32 + kc,                  unit q*16+m
// bm ballot layout: bm[(row_global*4 + chunk)*4 + j], j=col&3, bit=(col>>2)&63

// ================= K0: weight split + S=A+A^T split + Z init + adj ballot-pack =================
__global__ __launch_bounds__(256) void k_ph0(const float* __restrict__ Ww,
                                             const float* __restrict__ A,
                                             const float* __restrict__ adj,
                                             ushort* __restrict__ Whi, ushort* __restrict__ Wlo,
                                             ushort* __restrict__ Shi, ushort* __restrict__ Slo,
                                             float* __restrict__ Z, u64* __restrict__ bm) {
    int L = blockIdx.x, t = threadIdx.x;
    if (L < 64) {
        int i = L * 256 + t;
        float w = Ww[i];
        ushort wh = f2bf(w);
        Whi[i] = wh;
        Wlo[i] = f2bf(w - bf2f(wh));
        int e = i >> 7, d = i & 127;
        float s = A[i] + A[d * Dn + e];      // S = A + A^T (symmetrized bilinear form)
        ushort sh = f2bf(s);
        Shi[i] = sh;
        Slo[i] = f2bf(s - bf2f(sh));
        Z[i] = (float)Nn;                    // non-edge exp(0) mass, m=0 shift
    }
    int gwv = L * 4 + (t >> 6);
    int lane = t & 63;
    #pragma unroll 4
    for (int it = 0; it < 16; ++it) {
        int pair = gwv * 16 + it;            // (row,chunk), 65536 total
        const float* p = adj + (size_t)pair * 256 + lane * 4;
        float4 v = *(const float4*)p;
        u64 b0 = __ballot(v.x > 0.f);
        u64 b1 = __ballot(v.y > 0.f);
        u64 b2 = __ballot(v.z > 0.f);
        u64 b3 = __ballot(v.w > 0.f);
        if (lane == 0) {
            u64* d = bm + (size_t)pair * 4;
            d[0] = b0; d[1] = b1; d[2] = b2; d[3] = b3;
        }
    }
}

// ================= K1: h = xW^T+b ; g = h@S ; fragment bf16 out; x LDS-staged =================
__global__ __launch_bounds__(256) void k_h(const float* __restrict__ x,
                                           const float* __restrict__ Wb,
                                           const ushort* __restrict__ Whi,
                                           const ushort* __restrict__ Wlo,
                                           const ushort* __restrict__ Shi,
                                           const ushort* __restrict__ Slo,
                                           float* __restrict__ h,
                                           ushort* __restrict__ h16f,
                                           ushort* __restrict__ g16f) {
    int I0 = blockIdx.x * 16;
    int t = threadIdx.x, w = t >> 6, lane = t & 63;
    int m = lane & 15, q = lane >> 4;

    __shared__ float xs[16][Dn + 4];
    __shared__ float hs[16][Dn + 4];
    __shared__ float gs_[16][Dn + 4];

    {   // coalesced x stage: thread t -> row t>>4, cols (t&15)*8..+8
        int r = t >> 4, c8 = (t & 15) * 8;
        const float* src = x + (size_t)(I0 + r) * Dn + c8;
        *(float4*)&xs[r][c8]     = *(const float4*)(src);
        *(float4*)&xs[r][c8 + 4] = *(const float4*)(src + 4);
    }
    __syncthreads();

    f32x4 acc0 = {0,0,0,0}, acc1 = {0,0,0,0};
    #pragma unroll
    for (int ks = 0; ks < 4; ++ks) {
        int k0 = q * 8 + ks * 32;
        float v[8]; short8 ahi, alo;
        *(float4*)(v)     = *(const float4*)(&xs[m][k0]);
        *(float4*)(v + 4) = *(const float4*)(&xs[m][k0 + 4]);
        #pragma unroll
        for (int j = 0; j < 8; ++j) {
            ushort hi = f2bf(v[j]);
            ahi[j] = (short)hi;
            alo[j] = (short)f2bf(v[j] - bf2f(hi));
        }
        #pragma unroll
        for (int nn = 0; nn < 2; ++nn) {
            int brow = (w * 2 + nn) * 16 + m;
            short8 bhi = __builtin_bit_cast(short8, ((const us8*)(Whi + (size_t)brow * Dn))[q + ks * 4]);
            short8 blo = __builtin_bit_cast(short8, ((const us8*)(Wlo + (size_t)brow * Dn))[q + ks * 4]);
            f32x4 acc = nn ? acc1 : acc0;
            acc = __builtin_amdgcn_mfma_f32_16x16x32_bf16(ahi, bhi, acc, 0, 0, 0);
            acc = __builtin_amdgcn_mfma_f32_16x16x32_bf16(alo, bhi, acc, 0, 0, 0);
            acc = __builtin_amdgcn_mfma_f32_16x16x32_bf16(ahi, blo, acc, 0, 0, 0);
            if (nn) acc1 = acc; else acc0 = acc;
        }
    }
    #pragma unroll
    for (int nn = 0; nn < 2; ++nn) {
        int col = (w * 2 + nn) * 16 + m;
        float bias = Wb[col];
        f32x4 acc = nn ? acc1 : acc0;
        #pragma unroll
        for (int r = 0; r < 4; ++r) {
            int rl = q * 4 + r;
            float hv = acc[r] + bias;
            h[(size_t)(I0 + rl) * Dn + col] = hv;
            hs[rl][col] = hv;
        }
    }
    __syncthreads();

    f32x4 bcc0 = {0,0,0,0}, bcc1 = {0,0,0,0};
    #pragma unroll
    for (int ks = 0; ks < 4; ++ks) {
        int k0 = q * 8 + ks * 32;
        float v[8]; short8 ahi, alo;
        *(float4*)(v)     = *(const float4*)(&hs[m][k0]);
        *(float4*)(v + 4) = *(const float4*)(&hs[m][k0 + 4]);
        #pragma unroll
        for (int j = 0; j < 8; ++j) {
            ushort hi = f2bf(v[j]);
            ahi[j] = (short)hi;
            alo[j] = (short)f2bf(v[j] - bf2f(hi));
        }
        #pragma unroll
        for (int nn = 0; nn < 2; ++nn) {
            int brow = (w * 2 + nn) * 16 + m;
            short8 bhi = __builtin_bit_cast(short8, ((const us8*)(Shi + (size_t)brow * Dn))[q + ks * 4]);
            short8 blo = __builtin_bit_cast(short8, ((const us8*)(Slo + (size_t)brow * Dn))[q + ks * 4]);
            f32x4 acc = nn ? bcc1 : bcc0;
            acc = __builtin_amdgcn_mfma_f32_16x16x32_bf16(ahi, bhi, acc, 0, 0, 0);
            acc = __builtin_amdgcn_mfma_f32_16x16x32_bf16(alo, bhi, acc, 0, 0, 0);
            acc = __builtin_amdgcn_mfma_f32_16x16x32_bf16(ahi, blo, acc, 0, 0, 0);
            if (nn) bcc1 = acc; else bcc0 = acc;
        }
    }
    #pragma unroll
    for (int nn = 0; nn < 2; ++nn) {
        int col = (w * 2 + nn) * 16 + m;
        f32x4 acc = nn ? bcc1 : bcc0;
        #pragma unroll
        for (int r = 0; r < 4; ++r)
            gs_[q * 4 + r][col] = acc[r];
    }
    __syncthreads();

    {   // fragment-layout conversion (unit order q*16+m)
        int kc = t >> 6, mm = (t >> 2) & 15, qq = t & 3;
        int cb = kc * 32 + qq * 8;
        us8 oh, oa;
        #pragma unroll
        for (int e = 0; e < 8; ++e) {
            oh[e] = f2bf(hs[mm][cb + e]);
            oa[e] = f2bf(gs_[mm][cb + e]);
        }
        size_t U = (size_t)(I0 >> 4) * 256 + kc * 64 + qq * 16 + mm;
        ((us8*)h16f)[U] = oh;
        ((us8*)g16f)[U] = oa;
    }
}

// ================= K3: scores = g_I . h_J, A-frags in regs, h_J staged, linear frag reads ======
__global__ __launch_bounds__(256, 4) void k_scores(const ushort* __restrict__ g16f,
                                                   const ushort* __restrict__ h16f,
                                                   const u64* __restrict__ bm,
                                                   ushort* __restrict__ Ef,
                                                   float* __restrict__ Z) {
    int L = blockIdx.x;
    int b    = ((L & 7) << 1) | (L >> 11);        // XCD-grouped batches
    int tile = (L >> 3) & 255;
    int I0 = (tile >> 4) << 6;
    int J0 = (tile & 15) << 6;
    int t = threadIdx.x, wid = t >> 6, lane = t & 63;
    int loff = lane * 16;

    __shared__ __align__(16) char smem[18432];    // 16K h_J stage / 17K sc alias + 1K cz
    float (*sc)[68] = (float(*)[68])smem;
    float (*cz)[64] = (float(*)[64])(smem + 17408);

    {   // stage h_J: 16 x 1KB groups (rt_l = g>>2, kk = g&3)
        const char* hbp = (const char*)h16f + (size_t)b * 262144;
        for (int g = wid; g < 16; g += 4) {
            int rt_l = g >> 2, kk = g & 3;
            stage_group(hbp + ((size_t)((J0 >> 4) + rt_l) * 256 + kk * 64) * 16,
                        smem + g * 1024, lane);
        }
    }
    short8 afr[4];
    {   // g_I fragments straight to registers
        const char* gbp = (const char*)g16f + (size_t)b * 262144
                        + (size_t)((I0 >> 4) + wid) * 4096 + loff;
        #pragma unroll
        for (int ks = 0; ks < 4; ++ks)
            afr[ks] = __builtin_bit_cast(short8, *(const us8*)(gbp + ks * 1024));
    }
    __syncthreads();

    f32x4 acc[4] = {};
    #pragma unroll
    for (int ks = 0; ks < 4; ++ks) {
        #pragma unroll
        for (int nt = 0; nt < 4; ++nt) {
            short8 bb = __builtin_bit_cast(short8,
                *(const us8*)(smem + (nt * 4 + ks) * 1024 + loff));
            acc[nt] = __builtin_amdgcn_mfma_f32_16x16x32_bf16(afr[ks], bb, acc[nt], 0, 0, 0);
        }
    }
    __syncthreads();

    {
        int m = lane & 15, q = lane >> 4;
        #pragma unroll
        for (int nt = 0; nt < 4; ++nt)
            #pragma unroll
            for (int r = 0; r < 4; ++r)
                sc[wid * 16 + q * 4 + r][nt * 16 + m] = acc[nt][r];
    }
    __syncthreads();

    int row16 = t >> 4, c = t & 15;
    int bitc = ((J0 >> 2) & 63) + c;
    float colsum[4] = {0.f, 0.f, 0.f, 0.f};
    #pragma unroll
    for (int it = 0; it < 4; ++it) {
        int row = it * 16 + row16;
        const u64* wp = bm + ((size_t)(b * Nn + I0 + row) * 4 + (J0 >> 8)) * 4;
        u64 wj[4] = {wp[0], wp[1], wp[2], wp[3]};
        float s4[4];
        *(float4*)s4 = *(const float4*)(&sc[row][c * 4]);
        us4 e4;
        #pragma unroll
        for (int j = 0; j < 4; ++j) {
            float ex = __expf(s4[j]);
            bool on = (wj[j] >> bitc) & 1;
            e4[j] = f2bf(on ? ex : 0.f);
            colsum[j] += on ? (ex - 1.0f) : 0.f;
        }
        size_t base = ((((size_t)b * 64 + (I0 >> 4) + it) * 32 + (J0 >> 5) + (c >> 3)) * 512)
                    + (size_t)((c & 7) >> 1) * 128 + row16 * 8 + (c & 1) * 4;
        *(us4*)(Ef + base) = e4;
    }
    #pragma unroll
    for (int j = 0; j < 4; ++j) {
        colsum[j] += __shfl_xor(colsum[j], 16, 64);
        colsum[j] += __shfl_xor(colsum[j], 32, 64);
    }
    if (lane < 16) {
        #pragma unroll
        for (int j = 0; j < 4; ++j) cz[wid][lane * 4 + j] = colsum[j];
    }
    __syncthreads();
    if (t < 64) {
        float s = cz[0][t] + cz[1][t] + cz[2][t] + cz[3][t];
        atomicAdd(&Z[b * Nn + J0 + t], s);
    }
}

// ================= K4: Tf = fragment-layout (src/Z)^T =================
__global__ __launch_bounds__(256) void k_prep(const float* __restrict__ src,
                                              const float* __restrict__ Z,
                                              ushort* __restrict__ Tf) {
    int b = blockIdx.y;
    int j0 = blockIdx.x * 64;
    int t = threadIdx.x;
    __shared__ float ls[64][129];
    __shared__ float iz[64];
    if (t < 64) iz[t] = 1.0f / Z[b * Nn + j0 + t];
    __syncthreads();
    #pragma unroll
    for (int it = 0; it < 8; ++it) {              // float4 coalesced in
        int idx = it * 256 + t;
        int j = idx >> 5, k4 = (idx & 31) * 4;
        float4 v = *(const float4*)(src + ((size_t)b * Nn + j0 + j) * Dn + k4);
        float z = iz[j];
        ls[j][k4] = v.x * z; ls[j][k4 + 1] = v.y * z;
        ls[j][k4 + 2] = v.z * z; ls[j][k4 + 3] = v.w * z;
    }
    __syncthreads();
    int k = t & 127, half = t >> 7;
    us8 o[4];
    #pragma unroll
    for (int qq = 0; qq < 4; ++qq) {
        us8 tmp;
        #pragma unroll
        for (int e = 0; e < 8; ++e)
            tmp[e] = f2bf(ls[half * 32 + qq * 8 + e][k]);
        o[qq] = tmp;
    }
    size_t G = (size_t)(k >> 4) * 32 + (j0 >> 5) + half;
    ushort* dst = Tf + (size_t)b * 131072 + G * 512 + (size_t)(k & 15) * 8;
    #pragma unroll
    for (int qq = 0; qq < 4; ++qq)
        *(us8*)(dst + qq * 128) = o[qq];
}

// ================= K5: hop GEMM — K-split waves: zero redundant reads ==========================
// 8 waves = 4 row-tiles x 2 K-halves. E read once (disjoint K), Tf staged once (disjoint chunk
// ranges into per-stream LDS halves). 2-buf counted-vmcnt pipeline, 4 barriers/hop.
#define SSTAGE(BUF, gc) do {                                                           \
    _Pragma("unroll")                                                                  \
    for (int j = 0; j < 8; ++j) {                                                      \
        int g = rr * 8 + j;              /* g == kt*4+kk, kt=g>>2, kk=g&3 */           \
        stage_group(tfb + ((size_t)(g >> 2) * 32 + (gc) * 4 + (g & 3)) * 1024,         \
                    sbase + (BUF) * 32768 + g * 1024, lane);                           \
    }                                                                                  \
} while (0)

#define ELD(SET, gc) do {                                                              \
    _Pragma("unroll")                                                                  \
    for (int kk = 0; kk < 4; ++kk)                                                     \
        SET[kk] = __builtin_bit_cast(short8,                                           \
            *(const us8*)(ebase + ((gc) * 4 + kk) * 1024));                            \
} while (0)

#define SMFMA(BUF, SET) do {                                                           \
    __builtin_amdgcn_s_setprio(1);                                                     \
    _Pragma("unroll")                                                                  \
    for (int kk = 0; kk < 4; ++kk) {                                                   \
        _Pragma("unroll")                                                              \
        for (int nt = 0; nt < 8; ++nt) {                                               \
            short8 bf = __builtin_bit_cast(short8,                                     \
                *(const us8*)(sbase + (BUF) * 32768 + (nt * 4 + kk) * 1024 + loff));   \
            acc[nt] = __builtin_amdgcn_mfma_f32_16x16x32_bf16(SET[kk], bf, acc[nt], 0, 0, 0); \
        }                                                                              \
    }                                                                                  \
    __builtin_amdgcn_s_setprio(0);                                                     \
} while (0)

#define WAITB(NC) do {                                                                 \
    asm volatile("s_waitcnt vmcnt(" #NC ")" ::: "memory");                             \
    __builtin_amdgcn_s_barrier();                                                      \
} while (0)

__global__ __launch_bounds__(512, 1) void k_hop(const ushort* __restrict__ Ef,
                                                const ushort* __restrict__ Tf,
                                                const float* __restrict__ h,
                                                const float* __restrict__ Z,
                                                const float* __restrict__ gw,
                                                const float* __restrict__ gb,
                                                ushort* __restrict__ Tfn,
                                                float* __restrict__ out,
                                                int last) {
    int L = blockIdx.x;                           // 256 blocks, 1/CU (128 KB LDS)
    int b   = ((L & 7) << 1) | (L >> 7);          // XCD-grouped batches
    int rtp = (L >> 3) & 15;                      // block: rt = rtp*4 + {0..3}, 64 rows
    int t = threadIdx.x, w = t >> 6, lane = t & 63;
    int m = lane & 15, q = lane >> 4;
    int rr = w & 3, ks = w >> 2;                  // wave: row-tile rr, K-half ks
    int rt = rtp * 4 + rr;
    int I0 = rt << 4;
    int loff = lane * 16;

    __shared__ __align__(16) char smem[131072];   // 2 streams x 2 bufs x 32 KB
    char* sbase = smem + ks * 65536;

    const char* tfb   = (const char*)Tf + (size_t)b * 262144;
    const char* ebase = (const char*)Ef + (size_t)(b * 64 + rt) * 32768 + loff;

    // epilogue state (ks=0 waves own the full 16x128 output row block)
    float hv[8][4], izr[4], gwa[8], gwz[8];
    float gb0 = gb[0];
    size_t hbase = ((size_t)b * Nn + I0) * Dn;
    if (ks == 0) {
        #pragma unroll
        for (int r = 0; r < 4; ++r) izr[r] = 1.0f / Z[b * Nn + I0 + q * 4 + r];
        #pragma unroll
        for (int nt = 0; nt < 8; ++nt) {
            gwa[nt] = gw[nt * 16 + m];
            gwz[nt] = gw[Dn + nt * 16 + m];
            #pragma unroll
            for (int r = 0; r < 4; ++r)
                hv[nt][r] = h[hbase + (size_t)(q * 4 + r) * Dn + nt * 16 + m];
        }
    }
    asm volatile("s_waitcnt vmcnt(0)" ::: "memory");  // clean slate for counted waits

    int gc0 = ks * 4;                             // this stream's 4 chunks
    f32x4 acc[8] = {};
    short8 eA[4], eB[4];

    SSTAGE(0, gc0);     ELD(eA, gc0);
    WAITB(4);                                     // stage(buf0) retired; eA in flight
    SSTAGE(1, gc0 + 1); ELD(eB, gc0 + 1); SMFMA(0, eA);
    WAITB(4);
    SSTAGE(0, gc0 + 2); ELD(eA, gc0 + 2); SMFMA(1, eB);
    WAITB(4);
    SSTAGE(1, gc0 + 3); ELD(eB, gc0 + 3); SMFMA(0, eA);
    WAITB(4);
                                          SMFMA(1, eB);
    __syncthreads();                              // all MFMAs done; LDS reusable

    // combine K-halves: ks=1 writes partials to LDS (stream-1 area, dead), ks=0 adds
    float (*cmb)[8][16][16] = (float(*)[8][16][16])(smem + 65536);
    if (ks == 1) {
        #pragma unroll
        for (int nt = 0; nt < 8; ++nt)
            #pragma unroll
            for (int r = 0; r < 4; ++r)
                cmb[rr][nt][q * 4 + r][m] = acc[nt][r];
    }
    __syncthreads();

    ushort (*tt)[128][16] = (ushort(*)[128][16])smem;  // 16 KB, aliases stream-0 area (dead)
    if (ks == 0) {
        #pragma unroll
        for (int nt = 0; nt < 8; ++nt)
            #pragma unroll
            for (int r = 0; r < 4; ++r)
                acc[nt][r] += cmb[rr][nt][q * 4 + r][m];

        // gate: relu + shuffle-reduce over the 16 m-lanes (full row is wave-local now)
        float coef[4];
        #pragma unroll
        for (int r = 0; r < 4; ++r) {
            float gs = 0.f;
            #pragma unroll
            for (int nt = 0; nt < 8; ++nt) {
                float az = fmaxf(acc[nt][r], 0.f);
                acc[nt][r] = az;
                gs += hv[nt][r] * gwa[nt] + az * gwz[nt];
            }
            gs += __shfl_xor(gs, 1, 64);
            gs += __shfl_xor(gs, 2, 64);
            gs += __shfl_xor(gs, 4, 64);
            gs += __shfl_xor(gs, 8, 64);
            coef[r] = 1.0f / (1.0f + __expf(-(gs + gb0)));
        }

        if (last) {
            #pragma unroll
            for (int r = 0; r < 4; ++r) {
                float cc = coef[r];
                #pragma unroll
                for (int nt = 0; nt < 8; ++nt)
                    out[hbase + (size_t)(q * 4 + r) * Dn + nt * 16 + m] =
                        cc * hv[nt][r] + (1.f - cc) * acc[nt][r];
            }
        } else {
            #pragma unroll
            for (int r = 0; r < 4; ++r) {
                float cc = coef[r];
                float iz = izr[r];
                #pragma unroll
                for (int nt = 0; nt < 8; ++nt) {
                    float v = cc * hv[nt][r] + (1.f - cc) * acc[nt][r];
                    tt[rr][nt * 16 + m][q * 4 + r] = f2bf(v * iz);
                }
            }
        }
    }
    if (!last) {
        __syncthreads();
        // fragment-layout Tfn write (unit order qq*16 + (k&15)); 256 threads suffice
        if (t < 256) {
            int k = t >> 1, jh = t & 1;
            size_t G = (size_t)(k >> 4) * 32 + rtp * 2 + jh;
            ushort* dst = Tfn + (size_t)b * 131072 + G * 512 + (size_t)(k & 15) * 8;
            #pragma unroll
            for (int qq = 0; qq < 4; ++qq)
                *(us8*)(dst + qq * 128) = *(const us8*)&tt[jh * 2 + (qq >> 1)][k][(qq & 1) * 8];
        }
    }
}

extern "C" void kernel_launch(void* const* d_in, const int* in_sizes, int n_in,
                              void* d_out, int out_size, void* d_ws, size_t ws_size,
                              hipStream_t stream) {
    const float* x    = (const float*)d_in[0];   // [B,N,128]
    const float* adj  = (const float*)d_in[1];   // [B,N,N]
    const float* Ww   = (const float*)d_in[2];   // [128,128]
    const float* Wb   = (const float*)d_in[3];   // [128]
    const float* A    = (const float*)d_in[4];   // [128,128]
    const float* gw   = (const float*)d_in[5];   // [1,256]
    const float* gb   = (const float*)d_in[6];   // [1]
    float* out = (float*)d_out;                  // [B,N,128] f32

    char* ws = (char*)d_ws;
    float*  h    = (float*)(ws);                          // 8 MB f32
    ushort* Ta   = (ushort*)(ws + (8u << 20));            // 4 MB: h16f, then Tf buf A
    ushort* Tb   = (ushort*)(ws + (12u << 20));           // 4 MB: g16f, then Tf buf B
    ushort* E    = (ushort*)(ws + (16u << 20));           // 32 MB (fragment layout)
    float*  Z    = (float*)(ws + (48u << 20));            // 64 KB
    ushort* Whi  = (ushort*)(ws + (48u << 20) + (64u << 10));
    ushort* Wlo  = (ushort*)(ws + (48u << 20) + (96u << 10));
    ushort* Shi  = (ushort*)(ws + (48u << 20) + (128u << 10));
    ushort* Slo  = (ushort*)(ws + (48u << 20) + (160u << 10));
    u64*    bm   = (u64*)(ws + (48u << 20) + (192u << 10));  // 2 MB bitmask
    // total ~50.2 MB

    k_ph0   <<<1024, 256, 0, stream>>>(Ww, A, adj, Whi, Wlo, Shi, Slo, Z, bm);
    k_h     <<<1024, 256, 0, stream>>>(x, Wb, Whi, Wlo, Shi, Slo, h, Ta, Tb);
    k_scores<<<4096, 256, 0, stream>>>(Tb, Ta, bm, E, Z);
    k_prep  <<<dim3(16, Bn), 256, 0, stream>>>(h, Z, Ta);          // Tf0 = (h/Z)^T
    k_hop   <<<256, 512, 0, stream>>>(E, Ta, h, Z, gw, gb, Tb, out, 0);
    k_hop   <<<256, 512, 0, stream>>>(E, Tb, h, Z, gw, gb, Ta, out, 0);
    k_hop   <<<256, 512, 0, stream>>>(E, Ta, h, Z, gw, gb, (ushort*)nullptr, out, 1);
}